// Round 3
// baseline (783.584 us; speedup 1.0000x reference)
//
#include <hip/hip_runtime.h>
#include <hip/hip_bf16.h>

#define BB 32
#define NN 1024
#define WW 64
#define RR 4
#define IFD 471
#define OUTD 256
#define EPS 1e-6f

// ---------- ws layout (floats) ----------
// params:  [B][512]            0      .. 16384
// simw:    [B][N]              16384  .. 49152
// simr:    [B][N][R]           49152  .. 180224
// fw:      [B][N][R]           180224 .. 311296
// bw:      [B][N][R]           311296 .. 442368
#define WS_PARAMS 0
#define WS_SIMW   16384
#define WS_SIMR   49152
#define WS_FW     180224
#define WS_BW     311296

// params per-batch layout:
// 0:write_key[64] 64:write_vec[64] 128:erase[64] 192:free[4] 196:rstr[4]
// 200:wstr 201:wg 202:ag 203:key_norm 204:rk_norm[4] 208:mode[3][4]
// 224:read_keys[w][r] (256)

__device__ __forceinline__ float sigmoidf_(float x){ return 1.f/(1.f+expf(-x)); }
__device__ __forceinline__ float softplusf_(float x){ return fmaxf(x,0.f)+log1pf(expf(-fabsf(x))); }

__global__ void k_zero(float* p, int n){
  int i = blockIdx.x*256 + threadIdx.x;
  if (i < n) p[i] = 0.f;
}

__global__ void k_parse(const float* __restrict__ itf, float* __restrict__ P){
  int b = blockIdx.x; int t = threadIdx.x;
  const float* x = itf + b*IFD;
  float* p = P + b*512;
  if (t < 64){
    p[t]      = x[t];
    p[64+t]   = x[64+t];
    p[128+t]  = sigmoidf_(x[128+t]);
  }
  if (t < 4){
    p[192+t] = sigmoidf_(x[192+t]);
    p[196+t] = 1.f + softplusf_(x[196+t]);
  }
  if (t == 0){
    p[200] = 1.f + softplusf_(x[200]);
    p[201] = sigmoidf_(x[201]);
    p[202] = sigmoidf_(x[202]);
  }
  int w = t & 63, r = t >> 6;
  float rk = x[203 + r*64 + w];
  p[224 + w*4 + r] = rk;
  float s2 = rk*rk;
  for (int m=32;m;m>>=1) s2 += __shfl_xor(s2, m);
  if (w == 0) p[204 + r] = sqrtf(s2);
  float wk = (r==0) ? x[w] : 0.f;
  float k2 = wk*wk;
  for (int m=32;m;m>>=1) k2 += __shfl_xor(k2, m);
  if (t == 0) p[203] = sqrtf(k2);
  if (t < 4){
    float a0=x[459+t*3+0], a1=x[459+t*3+1], a2=x[459+t*3+2];
    float mx = fmaxf(a0, fmaxf(a1,a2));
    float e0=expf(a0-mx), e1=expf(a1-mx), e2=expf(a2-mx);
    float s = e0+e1+e2;
    p[208 + 0*4 + t] = e0/s;
    p[208 + 1*4 + t] = e1/s;
    p[208 + 2*4 + t] = e2/s;
  }
}

// usage + write-key similarity. 4 rows/block (1 wave each)
__global__ void k_usage_simw(const float* __restrict__ mem, const float* __restrict__ rwts,
                             const float* __restrict__ wwts, const float* __restrict__ usage_in,
                             const float* __restrict__ P, float* __restrict__ simw,
                             float* __restrict__ usage_out){
  int tid = threadIdx.x; int wid = tid>>6, lane = tid&63;
  size_t row = (size_t)blockIdx.x*4 + wid;
  int b = (int)(row >> 10);
  const float* p = P + b*512;
  float m = mem[row*64 + lane];
  float wk = p[lane];
  float s2 = m*m, sd = m*wk;
  for (int k=32;k;k>>=1){ s2+=__shfl_xor(s2,k); sd+=__shfl_xor(sd,k); }
  if (lane == 0){
    float norm = sqrtf(s2);
    simw[row] = sd / (norm * p[203] + EPS) * p[200];
    float4 r4 = *(const float4*)(rwts + row*4);
    float ret = (1.f - p[192]*r4.x)*(1.f - p[193]*r4.y)*(1.f - p[194]*r4.z)*(1.f - p[195]*r4.w);
    float pu = usage_in[row];
    float ww = wwts[row];
    usage_out[row] = (pu + ww - pu*ww) * ret;
  }
}

// per batch: alloc weighting (sort+scan), write softmax, write_w, precedence_new
__global__ __launch_bounds__(1024) void k_alloc_write(const float* __restrict__ simw,
    const float* __restrict__ usage, const float* __restrict__ prec,
    const float* __restrict__ P, float* __restrict__ write_w_out,
    float* __restrict__ prec_new_out){
  __shared__ float su[1024], sv[1024], sred[1024];
  __shared__ int sidx[1024];
  int t = threadIdx.x, b = blockIdx.x;
  const float* p = P + b*512;
  float u = EPS + (1.f-EPS)*usage[b*NN + t];
  su[t] = u; sidx[t] = t;
  __syncthreads();
  // bitonic sort ascending by (value, idx)  (== stable argsort)
  for (int k=2; k<=1024; k<<=1){
    for (int j=k>>1; j; j>>=1){
      int ixj = t ^ j;
      if (ixj > t){
        float a = su[t], c = su[ixj];
        int ia = sidx[t], ic = sidx[ixj];
        bool up = ((t & k) == 0);
        bool gt = (a > c) || (a == c && ia > ic);
        if (gt == up){ su[t]=c; su[ixj]=a; sidx[t]=ic; sidx[ixj]=ia; }
      }
      __syncthreads();
    }
  }
  sv[t] = su[t];       // u_sorted copy
  __syncthreads();
  // inclusive cumprod (Hillis-Steele)
  for (int off=1; off<1024; off<<=1){
    float y = (t >= off) ? su[t-off] : 1.f;
    __syncthreads();
    su[t] *= y;
    __syncthreads();
  }
  float excl = (t == 0) ? 1.f : su[t-1];
  float alloc_sorted = (1.f - sv[t]) * excl;
  sred[sidx[t]] = alloc_sorted;
  __syncthreads();
  float alloc = sred[t];
  // write-addr softmax
  float sim = simw[b*NN + t];
  sv[t] = sim; __syncthreads();
  for (int s=512; s; s>>=1){ if (t<s) sv[t] = fmaxf(sv[t], sv[t+s]); __syncthreads(); }
  float mx = sv[0]; __syncthreads();
  float e = expf(sim - mx);
  sv[t] = e; __syncthreads();
  for (int s=512; s; s>>=1){ if (t<s) sv[t] += sv[t+s]; __syncthreads(); }
  float wa = e / sv[0];
  float wg = p[201], ag = p[202];
  float ww = wg * ((1.f-ag)*wa + ag*alloc);
  write_w_out[b*NN + t] = ww;
  __syncthreads();
  sv[t] = ww; __syncthreads();
  for (int s=512; s; s>>=1){ if (t<s) sv[t] += sv[t+s]; __syncthreads(); }
  float S = sv[0];
  prec_new_out[b*NN + t] = (1.f - S)*prec[b*NN + t] + ww;
}

// memory update + read-key similarities
__global__ void k_memupd(const float* __restrict__ mem, const float* __restrict__ write_w,
                         const float* __restrict__ P, float* __restrict__ mu_out,
                         float* __restrict__ simr){
  int tid = threadIdx.x; int wid = tid>>6, lane = tid&63;
  size_t row = (size_t)blockIdx.x*4 + wid;
  int b = (int)(row >> 10);
  const float* p = P + b*512;
  float ww = write_w[row];
  float m = mem[row*64 + lane];
  float mu = m*(1.f - ww*p[128+lane]) + ww*p[64+lane];
  mu_out[row*64 + lane] = mu;
  float4 rk = *(const float4*)(p + 224 + lane*4);
  float s2 = mu*mu, d0 = mu*rk.x, d1 = mu*rk.y, d2 = mu*rk.z, d3 = mu*rk.w;
  for (int k=32;k;k>>=1){
    s2+=__shfl_xor(s2,k); d0+=__shfl_xor(d0,k); d1+=__shfl_xor(d1,k);
    d2+=__shfl_xor(d2,k); d3+=__shfl_xor(d3,k);
  }
  if (lane == 0){
    float norm = sqrtf(s2);
    float4 o;
    o.x = d0/(norm*p[204]+EPS)*p[196];
    o.y = d1/(norm*p[205]+EPS)*p[197];
    o.z = d2/(norm*p[206]+EPS)*p[198];
    o.w = d3/(norm*p[207]+EPS)*p[199];
    *(float4*)(simr + row*4) = o;
  }
}

// link_new + fused forward/backward. 16 blocks per batch, 64 rows per block.
__global__ __launch_bounds__(256) void k_link(const float* __restrict__ link,
    const float* __restrict__ rwts, const float* __restrict__ prec,
    const float* __restrict__ write_w, float* __restrict__ link_new,
    float* __restrict__ fw, float* __restrict__ bw){
  __shared__ float rwT[4][1024];
  __shared__ float sprec[1024], swcol[1024];
  __shared__ float sbacc[4][1024];
  int t = threadIdx.x, wid = t>>6, lane = t&63;
  int b = blockIdx.x >> 4;
  int rb = blockIdx.x & 15;
  const float* rwb = rwts + (size_t)b*NN*4;
  for (int i=t; i<1024; i+=256){
    float4 r4 = *(const float4*)(rwb + i*4);
    rwT[0][i]=r4.x; rwT[1][i]=r4.y; rwT[2][i]=r4.z; rwT[3][i]=r4.w;
    sprec[i] = prec[b*NN + i];
    swcol[i] = write_w[b*NN + i];
  }
  for (int i=t; i<4096; i+=256) ((float*)sbacc)[i] = 0.f;
  __syncthreads();
  const size_t lb = (size_t)b*NN*NN;
  for (int rr=0; rr<16; ++rr){
    int i = rb*64 + wid*16 + rr;
    float wn = swcol[i];
    float r0=rwT[0][i], r1=rwT[1][i], r2=rwT[2][i], r3=rwT[3][i];
    float f0=0.f, f1=0.f, f2=0.f, f3=0.f;
    const float* Lrow = link + lb + (size_t)i*NN;
    float* Orow = link_new + lb + (size_t)i*NN;
    for (int c=0; c<16; ++c){
      int j = (((c + wid*4) & 15) << 6) + lane;   // wave-staggered chunks
      float L = Lrow[j];
      float v = (1.f - wn + swcol[j])*L + wn*sprec[j];
      if (j == i) v = 0.f;
      Orow[j] = v;
      f0 += v*rwT[0][j]; f1 += v*rwT[1][j]; f2 += v*rwT[2][j]; f3 += v*rwT[3][j];
      atomicAdd(&sbacc[0][j], v*r0);
      atomicAdd(&sbacc[1][j], v*r1);
      atomicAdd(&sbacc[2][j], v*r2);
      atomicAdd(&sbacc[3][j], v*r3);
    }
    for (int k=32;k;k>>=1){ f0+=__shfl_xor(f0,k); f1+=__shfl_xor(f1,k); f2+=__shfl_xor(f2,k); f3+=__shfl_xor(f3,k); }
    if (lane == 0){
      float4 o = {f0,f1,f2,f3};
      *(float4*)(fw + ((size_t)b*NN + i)*4) = o;
    }
  }
  __syncthreads();
  for (int idx=t; idx<4096; idx+=256){
    int r = idx>>10, j = idx&1023;
    atomicAdd(&bw[((size_t)b*NN + j)*4 + r], sbacc[r][j]);
  }
}

// per batch: read softmax + combine modes -> read_w
__global__ void k_readw(const float* __restrict__ simr, const float* __restrict__ fw,
                        const float* __restrict__ bw, const float* __restrict__ P,
                        float* __restrict__ readw_out){
  __shared__ float ss[1024];
  __shared__ float red[256];
  int t = threadIdx.x, b = blockIdx.x;
  const float* p = P + b*512;
  for (int r=0; r<4; ++r){
    for (int i=t; i<1024; i+=256) ss[i] = simr[((size_t)b*NN + i)*4 + r];
    __syncthreads();
    float mx = -1e30f;
    for (int i=t; i<1024; i+=256) mx = fmaxf(mx, ss[i]);
    red[t] = mx; __syncthreads();
    for (int s=128; s; s>>=1){ if (t<s) red[t] = fmaxf(red[t], red[t+s]); __syncthreads(); }
    mx = red[0]; __syncthreads();
    float sm = 0.f;
    for (int i=t; i<1024; i+=256){ float e = expf(ss[i]-mx); ss[i] = e; sm += e; }
    red[t] = sm; __syncthreads();
    for (int s=128; s; s>>=1){ if (t<s) red[t] += red[t+s]; __syncthreads(); }
    float inv = 1.f/red[0];
    float m0 = p[208+r], m1 = p[212+r], m2 = p[216+r];
    for (int i=t; i<1024; i+=256){
      size_t idx = ((size_t)b*NN + i)*4 + r;
      readw_out[idx] = bw[idx]*m0 + ss[i]*inv*m1 + fw[idx]*m2;
    }
    __syncthreads();
  }
}

// read_vec partial accumulation (8 n-chunks per batch)
__global__ void k_readvec(const float* __restrict__ mu, const float* __restrict__ readw,
                          float* __restrict__ rv_out){
  int t = threadIdx.x;
  int b = blockIdx.x >> 3, ch = blockIdx.x & 7;
  int w = t & 63, r = t >> 6;
  float acc = 0.f;
  for (int n = ch*128; n < ch*128+128; ++n){
    size_t row = (size_t)b*NN + n;
    acc += mu[row*64 + w] * readw[row*4 + r];
  }
  atomicAdd(&rv_out[b*256 + w*4 + r], acc);
}

// memory_output = flat(read_vec) @ W_out + b_out
__global__ void k_out(const float* __restrict__ rv, const float* __restrict__ Wout,
                      const float* __restrict__ bout, float* __restrict__ out0){
  __shared__ float srv[256];
  int t = threadIdx.x, b = blockIdx.x;
  srv[t] = rv[b*256 + t];
  __syncthreads();
  float acc = bout[t];
  for (int k=0; k<256; ++k) acc += srv[k]*Wout[k*256 + t];
  out0[b*256 + t] = acc;
}

extern "C" void kernel_launch(void* const* d_in, const int* in_sizes, int n_in,
                              void* d_out, int out_size, void* d_ws, size_t ws_size,
                              hipStream_t stream) {
  const float* itf   = (const float*)d_in[0];
  const float* mem   = (const float*)d_in[1];
  const float* rwts  = (const float*)d_in[2];
  const float* wwts  = (const float*)d_in[3];
  const float* usage = (const float*)d_in[4];
  const float* prec  = (const float*)d_in[5];
  const float* link  = (const float*)d_in[6];
  const float* Wout  = (const float*)d_in[7];
  const float* bout  = (const float*)d_in[8];

  float* out = (float*)d_out;
  // output offsets (floats)
  float* o_memout   = out;                         // 8192
  float* o_mu       = out + 8192;                  // 2097152
  float* o_readw    = out + 8192 + 2097152;        // 131072
  float* o_writew   = o_readw + 131072;            // 32768
  float* o_readvec  = o_writew + 32768;            // 8192
  float* o_usage    = o_readvec + 8192;            // 32768
  float* o_precnew  = o_usage + 32768;             // 32768
  float* o_linknew  = o_precnew + 32768;           // 33554432

  float* ws = (float*)d_ws;
  float* P    = ws + WS_PARAMS;
  float* simw = ws + WS_SIMW;
  float* simr = ws + WS_SIMR;
  float* fw   = ws + WS_FW;
  float* bw   = ws + WS_BW;

  // zero accumulators (fw+bw contiguous, and read_vec output region)
  k_zero<<<(262144+255)/256, 256, 0, stream>>>(fw, 262144);
  k_zero<<<(8192+255)/256, 256, 0, stream>>>(o_readvec, 8192);

  k_parse<<<BB, 256, 0, stream>>>(itf, P);
  k_usage_simw<<<BB*NN/4, 256, 0, stream>>>(mem, rwts, wwts, usage, P, simw, o_usage);
  k_alloc_write<<<BB, 1024, 0, stream>>>(simw, o_usage, prec, P, o_writew, o_precnew);
  k_memupd<<<BB*NN/4, 256, 0, stream>>>(mem, o_writew, P, o_mu, simr);
  k_link<<<BB*16, 256, 0, stream>>>(link, rwts, prec, o_writew, o_linknew, fw, bw);
  k_readw<<<BB, 256, 0, stream>>>(simr, fw, bw, P, o_readw);
  k_readvec<<<BB*8, 256, 0, stream>>>(o_mu, o_readw, o_readvec);
  k_out<<<BB, 256, 0, stream>>>(o_readvec, Wout, bout, o_memout);
}

// Round 6
// 380.658 us; speedup vs baseline: 2.0585x; 2.0585x over previous
//
#include <hip/hip_runtime.h>
#include <hip/hip_bf16.h>

#define BB 32
#define NN 1024
#define WW 64
#define RR 4
#define IFD 471
#define OUTD 256
#define EPS 1e-6f

// ---------- ws layout (floats) ----------
#define WS_PARAMS 0
#define WS_SIMW   16384
#define WS_SIMR   49152
#define WS_FW     180224
#define WS_BW     311296

// params per-batch layout:
// 0:write_key[64] 64:write_vec[64] 128:erase[64] 192:free[4] 196:rstr[4]
// 200:wstr 201:wg 202:ag 203:key_norm 204:rk_norm[4] 208:mode[3][4]
// 224:read_keys[w][r] (256)

__device__ __forceinline__ float sigmoidf_(float x){ return 1.f/(1.f+expf(-x)); }
__device__ __forceinline__ float softplusf_(float x){ return fmaxf(x,0.f)+log1pf(expf(-fabsf(x))); }

__global__ void k_zero(float* p, int n){
  int i = blockIdx.x*256 + threadIdx.x;
  if (i < n) p[i] = 0.f;
}

__global__ void k_parse(const float* __restrict__ itf, float* __restrict__ P){
  int b = blockIdx.x; int t = threadIdx.x;
  const float* x = itf + b*IFD;
  float* p = P + b*512;
  if (t < 64){
    p[t]      = x[t];
    p[64+t]   = x[64+t];
    p[128+t]  = sigmoidf_(x[128+t]);
  }
  if (t < 4){
    p[192+t] = sigmoidf_(x[192+t]);
    p[196+t] = 1.f + softplusf_(x[196+t]);
  }
  if (t == 0){
    p[200] = 1.f + softplusf_(x[200]);
    p[201] = sigmoidf_(x[201]);
    p[202] = sigmoidf_(x[202]);
  }
  int w = t & 63, r = t >> 6;
  float rk = x[203 + r*64 + w];
  p[224 + w*4 + r] = rk;
  float s2 = rk*rk;
  for (int m=32;m;m>>=1) s2 += __shfl_xor(s2, m);
  if (w == 0) p[204 + r] = sqrtf(s2);
  float wk = (r==0) ? x[w] : 0.f;
  float k2 = wk*wk;
  for (int m=32;m;m>>=1) k2 += __shfl_xor(k2, m);
  if (t == 0) p[203] = sqrtf(k2);
  if (t < 4){
    float a0=x[459+t*3+0], a1=x[459+t*3+1], a2=x[459+t*3+2];
    float mx = fmaxf(a0, fmaxf(a1,a2));
    float e0=expf(a0-mx), e1=expf(a1-mx), e2=expf(a2-mx);
    float s = e0+e1+e2;
    p[208 + 0*4 + t] = e0/s;
    p[208 + 1*4 + t] = e1/s;
    p[208 + 2*4 + t] = e2/s;
  }
}

// usage + write-key similarity. 4 rows/block (1 wave each)
__global__ void k_usage_simw(const float* __restrict__ mem, const float* __restrict__ rwts,
                             const float* __restrict__ wwts, const float* __restrict__ usage_in,
                             const float* __restrict__ P, float* __restrict__ simw,
                             float* __restrict__ usage_out){
  int tid = threadIdx.x; int wid = tid>>6, lane = tid&63;
  size_t row = (size_t)blockIdx.x*4 + wid;
  int b = (int)(row >> 10);
  const float* p = P + b*512;
  float m = mem[row*64 + lane];
  float wk = p[lane];
  float s2 = m*m, sd = m*wk;
  for (int k=32;k;k>>=1){ s2+=__shfl_xor(s2,k); sd+=__shfl_xor(sd,k); }
  if (lane == 0){
    float norm = sqrtf(s2);
    simw[row] = sd / (norm * p[203] + EPS) * p[200];
    float4 r4 = *(const float4*)(rwts + row*4);
    float ret = (1.f - p[192]*r4.x)*(1.f - p[193]*r4.y)*(1.f - p[194]*r4.z)*(1.f - p[195]*r4.w);
    float pu = usage_in[row];
    float ww = wwts[row];
    usage_out[row] = (pu + ww - pu*ww) * ret;
  }
}

// per batch: alloc weighting (sort+scan), write softmax, write_w, precedence_new
__global__ __launch_bounds__(1024) void k_alloc_write(const float* __restrict__ simw,
    const float* __restrict__ usage, const float* __restrict__ prec,
    const float* __restrict__ P, float* __restrict__ write_w_out,
    float* __restrict__ prec_new_out){
  __shared__ float su[1024], sv[1024], sred[1024];
  __shared__ int sidx[1024];
  int t = threadIdx.x, b = blockIdx.x;
  const float* p = P + b*512;
  float u = EPS + (1.f-EPS)*usage[b*NN + t];
  su[t] = u; sidx[t] = t;
  __syncthreads();
  for (int k=2; k<=1024; k<<=1){
    for (int j=k>>1; j; j>>=1){
      int ixj = t ^ j;
      if (ixj > t){
        float a = su[t], c = su[ixj];
        int ia = sidx[t], ic = sidx[ixj];
        bool up = ((t & k) == 0);
        bool gt = (a > c) || (a == c && ia > ic);
        if (gt == up){ su[t]=c; su[ixj]=a; sidx[t]=ic; sidx[ixj]=ia; }
      }
      __syncthreads();
    }
  }
  sv[t] = su[t];
  __syncthreads();
  for (int off=1; off<1024; off<<=1){
    float y = (t >= off) ? su[t-off] : 1.f;
    __syncthreads();
    su[t] *= y;
    __syncthreads();
  }
  float excl = (t == 0) ? 1.f : su[t-1];
  float alloc_sorted = (1.f - sv[t]) * excl;
  sred[sidx[t]] = alloc_sorted;
  __syncthreads();
  float alloc = sred[t];
  float sim = simw[b*NN + t];
  sv[t] = sim; __syncthreads();
  for (int s=512; s; s>>=1){ if (t<s) sv[t] = fmaxf(sv[t], sv[t+s]); __syncthreads(); }
  float mx = sv[0]; __syncthreads();
  float e = expf(sim - mx);
  sv[t] = e; __syncthreads();
  for (int s=512; s; s>>=1){ if (t<s) sv[t] += sv[t+s]; __syncthreads(); }
  float wa = e / sv[0];
  float wg = p[201], ag = p[202];
  float ww = wg * ((1.f-ag)*wa + ag*alloc);
  write_w_out[b*NN + t] = ww;
  __syncthreads();
  sv[t] = ww; __syncthreads();
  for (int s=512; s; s>>=1){ if (t<s) sv[t] += sv[t+s]; __syncthreads(); }
  float S = sv[0];
  prec_new_out[b*NN + t] = (1.f - S)*prec[b*NN + t] + ww;
}

// memory update + read-key similarities
__global__ void k_memupd(const float* __restrict__ mem, const float* __restrict__ write_w,
                         const float* __restrict__ P, float* __restrict__ mu_out,
                         float* __restrict__ simr){
  int tid = threadIdx.x; int wid = tid>>6, lane = tid&63;
  size_t row = (size_t)blockIdx.x*4 + wid;
  int b = (int)(row >> 10);
  const float* p = P + b*512;
  float ww = write_w[row];
  float m = mem[row*64 + lane];
  float mu = m*(1.f - ww*p[128+lane]) + ww*p[64+lane];
  mu_out[row*64 + lane] = mu;
  float4 rk = *(const float4*)(p + 224 + lane*4);
  float s2 = mu*mu, d0 = mu*rk.x, d1 = mu*rk.y, d2 = mu*rk.z, d3 = mu*rk.w;
  for (int k=32;k;k>>=1){
    s2+=__shfl_xor(s2,k); d0+=__shfl_xor(d0,k); d1+=__shfl_xor(d1,k);
    d2+=__shfl_xor(d2,k); d3+=__shfl_xor(d3,k);
  }
  if (lane == 0){
    float norm = sqrtf(s2);
    float4 o;
    o.x = d0/(norm*p[204]+EPS)*p[196];
    o.y = d1/(norm*p[205]+EPS)*p[197];
    o.z = d2/(norm*p[206]+EPS)*p[198];
    o.w = d3/(norm*p[207]+EPS)*p[199];
    *(float4*)(simr + row*4) = o;
  }
}

// link_new + fused fw/bw. Lane owns 4 columns (whole block = full 1024-col row
// width); block owns 32 rows; 32 row-blocks per batch. No LDS atomics, no LDS
// tile: bw accumulates in registers (column-owned), fw via per-row wave
// shuffle-reduce + cross-wave LDS combine, direct store (rows block-exclusive).
__global__ __launch_bounds__(256) void k_link(const float* __restrict__ link,
    const float* __restrict__ rwts, const float* __restrict__ prec,
    const float* __restrict__ write_w, float* __restrict__ link_new,
    float* __restrict__ fw, float* __restrict__ bw){
  __shared__ float4 sfw[4][32];
  int t = threadIdx.x, wid = t>>6, lane = t&63;
  int b  = blockIdx.x >> 5;
  int rb = blockIdx.x & 31;
  int col0 = t*4;
  const size_t base = (size_t)b*NN;
  const size_t lb   = (size_t)b*NN*NN;
  float4 wj = *(const float4*)(write_w + base + col0);
  float4 pj = *(const float4*)(prec + base + col0);
  float4 rj0 = *(const float4*)(rwts + (base + col0+0)*4);
  float4 rj1 = *(const float4*)(rwts + (base + col0+1)*4);
  float4 rj2 = *(const float4*)(rwts + (base + col0+2)*4);
  float4 rj3 = *(const float4*)(rwts + (base + col0+3)*4);
  float4 bw0 = {0,0,0,0}, bw1 = {0,0,0,0}, bw2 = {0,0,0,0}, bw3 = {0,0,0,0};
  #pragma unroll 4
  for (int ii=0; ii<32; ++ii){
    int i = rb*32 + ii;
    float wi = write_w[base + i];
    float4 ri = *(const float4*)(rwts + (base + i)*4);
    float4 L4 = *(const float4*)(link + lb + (size_t)i*NN + col0);
    float om = 1.f - wi;
    float4 v;
    v.x = fmaf(om + wj.x, L4.x, wi*pj.x);
    v.y = fmaf(om + wj.y, L4.y, wi*pj.y);
    v.z = fmaf(om + wj.z, L4.z, wi*pj.z);
    v.w = fmaf(om + wj.w, L4.w, wi*pj.w);
    v.x = (i == col0  ) ? 0.f : v.x;
    v.y = (i == col0+1) ? 0.f : v.y;
    v.z = (i == col0+2) ? 0.f : v.z;
    v.w = (i == col0+3) ? 0.f : v.w;
    *(float4*)(link_new + lb + (size_t)i*NN + col0) = v;
    // bw: column-owned register accumulation
    bw0.x = fmaf(v.x, ri.x, bw0.x); bw0.y = fmaf(v.x, ri.y, bw0.y);
    bw0.z = fmaf(v.x, ri.z, bw0.z); bw0.w = fmaf(v.x, ri.w, bw0.w);
    bw1.x = fmaf(v.y, ri.x, bw1.x); bw1.y = fmaf(v.y, ri.y, bw1.y);
    bw1.z = fmaf(v.y, ri.z, bw1.z); bw1.w = fmaf(v.y, ri.w, bw1.w);
    bw2.x = fmaf(v.z, ri.x, bw2.x); bw2.y = fmaf(v.z, ri.y, bw2.y);
    bw2.z = fmaf(v.z, ri.z, bw2.z); bw2.w = fmaf(v.z, ri.w, bw2.w);
    bw3.x = fmaf(v.w, ri.x, bw3.x); bw3.y = fmaf(v.w, ri.y, bw3.y);
    bw3.z = fmaf(v.w, ri.z, bw3.z); bw3.w = fmaf(v.w, ri.w, bw3.w);
    // fw partial for this row across this thread's 4 columns
    float p0 = v.x*rj0.x + v.y*rj1.x + v.z*rj2.x + v.w*rj3.x;
    float p1 = v.x*rj0.y + v.y*rj1.y + v.z*rj2.y + v.w*rj3.y;
    float p2 = v.x*rj0.z + v.y*rj1.z + v.z*rj2.z + v.w*rj3.z;
    float p3 = v.x*rj0.w + v.y*rj1.w + v.z*rj2.w + v.w*rj3.w;
    for (int k=32;k;k>>=1){
      p0 += __shfl_xor(p0,k); p1 += __shfl_xor(p1,k);
      p2 += __shfl_xor(p2,k); p3 += __shfl_xor(p3,k);
    }
    if (lane == 0){ float4 o = {p0,p1,p2,p3}; sfw[wid][ii] = o; }
  }
  __syncthreads();
  if (t < 128){
    int ii = t>>2, r = t&3;
    float s = ((const float*)&sfw[0][ii])[r] + ((const float*)&sfw[1][ii])[r]
            + ((const float*)&sfw[2][ii])[r] + ((const float*)&sfw[3][ii])[r];
    fw[(base + (size_t)rb*32 + ii)*4 + r] = s;
  }
  float* bwp = bw + (base + col0)*4;
  atomicAdd(bwp+0,  bw0.x); atomicAdd(bwp+1,  bw0.y); atomicAdd(bwp+2,  bw0.z); atomicAdd(bwp+3,  bw0.w);
  atomicAdd(bwp+4,  bw1.x); atomicAdd(bwp+5,  bw1.y); atomicAdd(bwp+6,  bw1.z); atomicAdd(bwp+7,  bw1.w);
  atomicAdd(bwp+8,  bw2.x); atomicAdd(bwp+9,  bw2.y); atomicAdd(bwp+10, bw2.z); atomicAdd(bwp+11, bw2.w);
  atomicAdd(bwp+12, bw3.x); atomicAdd(bwp+13, bw3.y); atomicAdd(bwp+14, bw3.z); atomicAdd(bwp+15, bw3.w);
}

// per batch: read softmax + combine modes -> read_w
__global__ void k_readw(const float* __restrict__ simr, const float* __restrict__ fw,
                        const float* __restrict__ bw, const float* __restrict__ P,
                        float* __restrict__ readw_out){
  __shared__ float ss[1024];
  __shared__ float red[256];
  int t = threadIdx.x, b = blockIdx.x;
  const float* p = P + b*512;
  for (int r=0; r<4; ++r){
    for (int i=t; i<1024; i+=256) ss[i] = simr[((size_t)b*NN + i)*4 + r];
    __syncthreads();
    float mx = -1e30f;
    for (int i=t; i<1024; i+=256) mx = fmaxf(mx, ss[i]);
    red[t] = mx; __syncthreads();
    for (int s=128; s; s>>=1){ if (t<s) red[t] = fmaxf(red[t], red[t+s]); __syncthreads(); }
    mx = red[0]; __syncthreads();
    float sm = 0.f;
    for (int i=t; i<1024; i+=256){ float e = expf(ss[i]-mx); ss[i] = e; sm += e; }
    red[t] = sm; __syncthreads();
    for (int s=128; s; s>>=1){ if (t<s) red[t] += red[t+s]; __syncthreads(); }
    float inv = 1.f/red[0];
    float m0 = p[208+r], m1 = p[212+r], m2 = p[216+r];
    for (int i=t; i<1024; i+=256){
      size_t idx = ((size_t)b*NN + i)*4 + r;
      readw_out[idx] = bw[idx]*m0 + ss[i]*inv*m1 + fw[idx]*m2;
    }
    __syncthreads();
  }
}

// read_vec partial accumulation (8 n-chunks per batch)
__global__ void k_readvec(const float* __restrict__ mu, const float* __restrict__ readw,
                          float* __restrict__ rv_out){
  int t = threadIdx.x;
  int b = blockIdx.x >> 3, ch = blockIdx.x & 7;
  int w = t & 63, r = t >> 6;
  float acc = 0.f;
  for (int n = ch*128; n < ch*128+128; ++n){
    size_t row = (size_t)b*NN + n;
    acc += mu[row*64 + w] * readw[row*4 + r];
  }
  atomicAdd(&rv_out[b*256 + w*4 + r], acc);
}

// memory_output = flat(read_vec) @ W_out + b_out
__global__ void k_out(const float* __restrict__ rv, const float* __restrict__ Wout,
                      const float* __restrict__ bout, float* __restrict__ out0){
  __shared__ float srv[256];
  int t = threadIdx.x, b = blockIdx.x;
  srv[t] = rv[b*256 + t];
  __syncthreads();
  float acc = bout[t];
  for (int k=0; k<256; ++k) acc += srv[k]*Wout[k*256 + t];
  out0[b*256 + t] = acc;
}

extern "C" void kernel_launch(void* const* d_in, const int* in_sizes, int n_in,
                              void* d_out, int out_size, void* d_ws, size_t ws_size,
                              hipStream_t stream) {
  const float* itf   = (const float*)d_in[0];
  const float* mem   = (const float*)d_in[1];
  const float* rwts  = (const float*)d_in[2];
  const float* wwts  = (const float*)d_in[3];
  const float* usage = (const float*)d_in[4];
  const float* prec  = (const float*)d_in[5];
  const float* link  = (const float*)d_in[6];
  const float* Wout  = (const float*)d_in[7];
  const float* bout  = (const float*)d_in[8];

  float* out = (float*)d_out;
  float* o_memout   = out;                         // 8192
  float* o_mu       = out + 8192;                  // 2097152
  float* o_readw    = out + 8192 + 2097152;        // 131072
  float* o_writew   = o_readw + 131072;            // 32768
  float* o_readvec  = o_writew + 32768;            // 8192
  float* o_usage    = o_readvec + 8192;             // 32768
  float* o_precnew  = o_usage + 32768;             // 32768
  float* o_linknew  = o_precnew + 32768;           // 33554432

  float* ws = (float*)d_ws;
  float* P    = ws + WS_PARAMS;
  float* simw = ws + WS_SIMW;
  float* simr = ws + WS_SIMR;
  float* fw   = ws + WS_FW;
  float* bw   = ws + WS_BW;

  // zero bw accumulator + read_vec output region (fw is direct-stored)
  k_zero<<<(131072+255)/256, 256, 0, stream>>>(bw, 131072);
  k_zero<<<(8192+255)/256, 256, 0, stream>>>(o_readvec, 8192);

  k_parse<<<BB, 256, 0, stream>>>(itf, P);
  k_usage_simw<<<BB*NN/4, 256, 0, stream>>>(mem, rwts, wwts, usage, P, simw, o_usage);
  k_alloc_write<<<BB, 1024, 0, stream>>>(simw, o_usage, prec, P, o_writew, o_precnew);
  k_memupd<<<BB*NN/4, 256, 0, stream>>>(mem, o_writew, P, o_mu, simr);
  k_link<<<BB*32, 256, 0, stream>>>(link, rwts, prec, o_writew, o_linknew, fw, bw);
  k_readw<<<BB, 256, 0, stream>>>(simr, fw, bw, P, o_readw);
  k_readvec<<<BB*8, 256, 0, stream>>>(o_mu, o_readw, o_readvec);
  k_out<<<BB, 256, 0, stream>>>(o_readvec, Wout, bout, o_memout);
}

// Round 7
// 141.664 us; speedup vs baseline: 5.5313x; 2.6870x over previous
//
#include <hip/hip_runtime.h>
#include <hip/hip_bf16.h>

#define BB 32
#define NN 1024
#define WW 64
#define RR 4
#define IFD 471
#define OUTD 256
#define EPS 1e-6f

// ---------- ws layout (floats) ----------
#define WS_PARAMS 0
#define WS_SIMW   16384
#define WS_SIMR   49152
#define WS_FW     180224
#define WS_BW     311296

// params per-batch layout:
// 0:write_key[64] 64:write_vec[64] 128:erase[64] 192:free[4] 196:rstr[4]
// 200:wstr 201:wg 202:ag 203:key_norm 204:rk_norm[4] 208:mode[3][4]
// 224:read_keys[w][r] (256)

__device__ __forceinline__ float sigmoidf_(float x){ return 1.f/(1.f+expf(-x)); }
__device__ __forceinline__ float softplusf_(float x){ return fmaxf(x,0.f)+log1pf(expf(-fabsf(x))); }

__global__ void k_zero(float* p, int n){
  int i = blockIdx.x*256 + threadIdx.x;
  if (i < n) p[i] = 0.f;
}

__global__ void k_parse(const float* __restrict__ itf, float* __restrict__ P){
  int b = blockIdx.x; int t = threadIdx.x;
  const float* x = itf + b*IFD;
  float* p = P + b*512;
  if (t < 64){
    p[t]      = x[t];
    p[64+t]   = x[64+t];
    p[128+t]  = sigmoidf_(x[128+t]);
  }
  if (t < 4){
    p[192+t] = sigmoidf_(x[192+t]);
    p[196+t] = 1.f + softplusf_(x[196+t]);
  }
  if (t == 0){
    p[200] = 1.f + softplusf_(x[200]);
    p[201] = sigmoidf_(x[201]);
    p[202] = sigmoidf_(x[202]);
  }
  int w = t & 63, r = t >> 6;
  float rk = x[203 + r*64 + w];
  p[224 + w*4 + r] = rk;
  float s2 = rk*rk;
  for (int m=32;m;m>>=1) s2 += __shfl_xor(s2, m);
  if (w == 0) p[204 + r] = sqrtf(s2);
  float wk = (r==0) ? x[w] : 0.f;
  float k2 = wk*wk;
  for (int m=32;m;m>>=1) k2 += __shfl_xor(k2, m);
  if (t == 0) p[203] = sqrtf(k2);
  if (t < 4){
    float a0=x[459+t*3+0], a1=x[459+t*3+1], a2=x[459+t*3+2];
    float mx = fmaxf(a0, fmaxf(a1,a2));
    float e0=expf(a0-mx), e1=expf(a1-mx), e2=expf(a2-mx);
    float s = e0+e1+e2;
    p[208 + 0*4 + t] = e0/s;
    p[208 + 1*4 + t] = e1/s;
    p[208 + 2*4 + t] = e2/s;
  }
}

// usage + write-key similarity. 4 rows/block (1 wave each)
__global__ void k_usage_simw(const float* __restrict__ mem, const float* __restrict__ rwts,
                             const float* __restrict__ wwts, const float* __restrict__ usage_in,
                             const float* __restrict__ P, float* __restrict__ simw,
                             float* __restrict__ usage_out){
  int tid = threadIdx.x; int wid = tid>>6, lane = tid&63;
  size_t row = (size_t)blockIdx.x*4 + wid;
  int b = (int)(row >> 10);
  const float* p = P + b*512;
  float m = mem[row*64 + lane];
  float wk = p[lane];
  float s2 = m*m, sd = m*wk;
  for (int k=32;k;k>>=1){ s2+=__shfl_xor(s2,k); sd+=__shfl_xor(sd,k); }
  if (lane == 0){
    float norm = sqrtf(s2);
    simw[row] = sd / (norm * p[203] + EPS) * p[200];
    float4 r4 = *(const float4*)(rwts + row*4);
    float ret = (1.f - p[192]*r4.x)*(1.f - p[193]*r4.y)*(1.f - p[194]*r4.z)*(1.f - p[195]*r4.w);
    float pu = usage_in[row];
    float ww = wwts[row];
    usage_out[row] = (pu + ww - pu*ww) * ret;
  }
}

// per batch: alloc weighting (sort+scan), write softmax, write_w, precedence_new
__global__ __launch_bounds__(1024) void k_alloc_write(const float* __restrict__ simw,
    const float* __restrict__ usage, const float* __restrict__ prec,
    const float* __restrict__ P, float* __restrict__ write_w_out,
    float* __restrict__ prec_new_out){
  __shared__ float su[1024], sv[1024], sred[1024];
  __shared__ int sidx[1024];
  int t = threadIdx.x, b = blockIdx.x;
  const float* p = P + b*512;
  float u = EPS + (1.f-EPS)*usage[b*NN + t];
  su[t] = u; sidx[t] = t;
  __syncthreads();
  for (int k=2; k<=1024; k<<=1){
    for (int j=k>>1; j; j>>=1){
      int ixj = t ^ j;
      if (ixj > t){
        float a = su[t], c = su[ixj];
        int ia = sidx[t], ic = sidx[ixj];
        bool up = ((t & k) == 0);
        bool gt = (a > c) || (a == c && ia > ic);
        if (gt == up){ su[t]=c; su[ixj]=a; sidx[t]=ic; sidx[ixj]=ia; }
      }
      __syncthreads();
    }
  }
  sv[t] = su[t];
  __syncthreads();
  for (int off=1; off<1024; off<<=1){
    float y = (t >= off) ? su[t-off] : 1.f;
    __syncthreads();
    su[t] *= y;
    __syncthreads();
  }
  float excl = (t == 0) ? 1.f : su[t-1];
  float alloc_sorted = (1.f - sv[t]) * excl;
  sred[sidx[t]] = alloc_sorted;
  __syncthreads();
  float alloc = sred[t];
  float sim = simw[b*NN + t];
  sv[t] = sim; __syncthreads();
  for (int s=512; s; s>>=1){ if (t<s) sv[t] = fmaxf(sv[t], sv[t+s]); __syncthreads(); }
  float mx = sv[0]; __syncthreads();
  float e = expf(sim - mx);
  sv[t] = e; __syncthreads();
  for (int s=512; s; s>>=1){ if (t<s) sv[t] += sv[t+s]; __syncthreads(); }
  float wa = e / sv[0];
  float wg = p[201], ag = p[202];
  float ww = wg * ((1.f-ag)*wa + ag*alloc);
  write_w_out[b*NN + t] = ww;
  __syncthreads();
  sv[t] = ww; __syncthreads();
  for (int s=512; s; s>>=1){ if (t<s) sv[t] += sv[t+s]; __syncthreads(); }
  float S = sv[0];
  prec_new_out[b*NN + t] = (1.f - S)*prec[b*NN + t] + ww;
}

// memory update + read-key similarities
__global__ void k_memupd(const float* __restrict__ mem, const float* __restrict__ write_w,
                         const float* __restrict__ P, float* __restrict__ mu_out,
                         float* __restrict__ simr){
  int tid = threadIdx.x; int wid = tid>>6, lane = tid&63;
  size_t row = (size_t)blockIdx.x*4 + wid;
  int b = (int)(row >> 10);
  const float* p = P + b*512;
  float ww = write_w[row];
  float m = mem[row*64 + lane];
  float mu = m*(1.f - ww*p[128+lane]) + ww*p[64+lane];
  mu_out[row*64 + lane] = mu;
  float4 rk = *(const float4*)(p + 224 + lane*4);
  float s2 = mu*mu, d0 = mu*rk.x, d1 = mu*rk.y, d2 = mu*rk.z, d3 = mu*rk.w;
  for (int k=32;k;k>>=1){
    s2+=__shfl_xor(s2,k); d0+=__shfl_xor(d0,k); d1+=__shfl_xor(d1,k);
    d2+=__shfl_xor(d2,k); d3+=__shfl_xor(d3,k);
  }
  if (lane == 0){
    float norm = sqrtf(s2);
    float4 o;
    o.x = d0/(norm*p[204]+EPS)*p[196];
    o.y = d1/(norm*p[205]+EPS)*p[197];
    o.z = d2/(norm*p[206]+EPS)*p[198];
    o.w = d3/(norm*p[207]+EPS)*p[199];
    *(float4*)(simr + row*4) = o;
  }
}

// link_new + fused fw/bw, tile version. 64x64 tile per block, 256 threads as
// 16(tx) x 16(ty), each thread a 4row x 4col subtile. fw AND bw partials in
// registers (no cross-lane ops in loop); one LDS reduce at block end; one
// atomicAdd per thread per output. Grid: b(32) x rt(16) x ct(16) = 8192.
__global__ __launch_bounds__(256) void k_link(const float* __restrict__ link,
    const float* __restrict__ rwts, const float* __restrict__ prec,
    const float* __restrict__ write_w, float* __restrict__ link_new,
    float* __restrict__ fw, float* __restrict__ bw){
  __shared__ float red[4352];           // 255*17+16 slots, 17 KB, reused twice
  int t = threadIdx.x;
  int tx = t & 15, ty = t >> 4;
  int bid = blockIdx.x;
  int b  = bid >> 8;
  int rt = (bid >> 4) & 15;
  int ct = bid & 15;
  int row0 = rt*64 + ty*4;
  int col0 = ct*64 + tx*4;
  const size_t base = (size_t)b*NN;
  const size_t lb   = (size_t)b*NN*NN;
  // column-side params (this thread's 4 cols)
  float4 wj = *(const float4*)(write_w + base + col0);
  float4 pj = *(const float4*)(prec + base + col0);
  float4 rj0 = *(const float4*)(rwts + (base + col0+0)*4);
  float4 rj1 = *(const float4*)(rwts + (base + col0+1)*4);
  float4 rj2 = *(const float4*)(rwts + (base + col0+2)*4);
  float4 rj3 = *(const float4*)(rwts + (base + col0+3)*4);
  // row-side params (this thread's 4 rows)
  float wi0 = write_w[base + row0+0], wi1 = write_w[base + row0+1];
  float wi2 = write_w[base + row0+2], wi3 = write_w[base + row0+3];
  float4 ri0 = *(const float4*)(rwts + (base + row0+0)*4);
  float4 ri1 = *(const float4*)(rwts + (base + row0+1)*4);
  float4 ri2 = *(const float4*)(rwts + (base + row0+2)*4);
  float4 ri3 = *(const float4*)(rwts + (base + row0+3)*4);
  float fwacc[4][4];                    // [dr][r]
  float bwacc[4][4];                    // [dc][r]
  #pragma unroll
  for (int a=0;a<4;++a) for (int c=0;c<4;++c){ fwacc[a][c]=0.f; bwacc[a][c]=0.f; }
  #pragma unroll
  for (int dr=0; dr<4; ++dr){
    int i = row0 + dr;
    float wi = (dr==0)?wi0:(dr==1)?wi1:(dr==2)?wi2:wi3;
    float4 ri = (dr==0)?ri0:(dr==1)?ri1:(dr==2)?ri2:ri3;
    float4 L4 = *(const float4*)(link + lb + (size_t)i*NN + col0);
    float om = 1.f - wi;
    float4 v;
    v.x = fmaf(om + wj.x, L4.x, wi*pj.x);
    v.y = fmaf(om + wj.y, L4.y, wi*pj.y);
    v.z = fmaf(om + wj.z, L4.z, wi*pj.z);
    v.w = fmaf(om + wj.w, L4.w, wi*pj.w);
    v.x = (i == col0  ) ? 0.f : v.x;
    v.y = (i == col0+1) ? 0.f : v.y;
    v.z = (i == col0+2) ? 0.f : v.z;
    v.w = (i == col0+3) ? 0.f : v.w;
    *(float4*)(link_new + lb + (size_t)i*NN + col0) = v;
    // fw[row i] partial over this thread's 4 cols
    fwacc[dr][0] += v.x*rj0.x + v.y*rj1.x + v.z*rj2.x + v.w*rj3.x;
    fwacc[dr][1] += v.x*rj0.y + v.y*rj1.y + v.z*rj2.y + v.w*rj3.y;
    fwacc[dr][2] += v.x*rj0.z + v.y*rj1.z + v.z*rj2.z + v.w*rj3.z;
    fwacc[dr][3] += v.x*rj0.w + v.y*rj1.w + v.z*rj2.w + v.w*rj3.w;
    // bw[col] partial over this thread's 4 rows
    bwacc[0][0] = fmaf(v.x, ri.x, bwacc[0][0]); bwacc[0][1] = fmaf(v.x, ri.y, bwacc[0][1]);
    bwacc[0][2] = fmaf(v.x, ri.z, bwacc[0][2]); bwacc[0][3] = fmaf(v.x, ri.w, bwacc[0][3]);
    bwacc[1][0] = fmaf(v.y, ri.x, bwacc[1][0]); bwacc[1][1] = fmaf(v.y, ri.y, bwacc[1][1]);
    bwacc[1][2] = fmaf(v.y, ri.z, bwacc[1][2]); bwacc[1][3] = fmaf(v.y, ri.w, bwacc[1][3]);
    bwacc[2][0] = fmaf(v.z, ri.x, bwacc[2][0]); bwacc[2][1] = fmaf(v.z, ri.y, bwacc[2][1]);
    bwacc[2][2] = fmaf(v.z, ri.z, bwacc[2][2]); bwacc[2][3] = fmaf(v.z, ri.w, bwacc[2][3]);
    bwacc[3][0] = fmaf(v.w, ri.x, bwacc[3][0]); bwacc[3][1] = fmaf(v.w, ri.y, bwacc[3][1]);
    bwacc[3][2] = fmaf(v.w, ri.z, bwacc[3][2]); bwacc[3][3] = fmaf(v.w, ri.w, bwacc[3][3]);
  }
  // ---- fw reduce over tx: stage [rowl(64)][r(4)] x tx(16), stride 17
  #pragma unroll
  for (int dr=0; dr<4; ++dr)
    #pragma unroll
    for (int r=0; r<4; ++r)
      red[((ty*4+dr)*4 + r)*17 + tx] = fwacc[dr][r];
  __syncthreads();
  {
    int rowl = t >> 2, r = t & 3;
    const float* q = red + (rowl*4 + r)*17;
    float s = 0.f;
    #pragma unroll
    for (int i=0; i<16; ++i) s += q[i];
    atomicAdd(&fw[(base + rt*64 + rowl)*4 + r], s);
  }
  __syncthreads();
  // ---- bw reduce over ty: stage [r(4)][coll(64)] x ty(16), stride 17
  #pragma unroll
  for (int dc=0; dc<4; ++dc)
    #pragma unroll
    for (int r=0; r<4; ++r)
      red[((r*64) + (tx*4+dc))*17 + ty] = bwacc[dc][r];
  __syncthreads();
  {
    int coll = t >> 2, r = t & 3;
    const float* q = red + (r*64 + coll)*17;
    float s = 0.f;
    #pragma unroll
    for (int i=0; i<16; ++i) s += q[i];
    atomicAdd(&bw[(base + ct*64 + coll)*4 + r], s);
  }
}

// per batch: read softmax + combine modes -> read_w
__global__ void k_readw(const float* __restrict__ simr, const float* __restrict__ fw,
                        const float* __restrict__ bw, const float* __restrict__ P,
                        float* __restrict__ readw_out){
  __shared__ float ss[1024];
  __shared__ float red[256];
  int t = threadIdx.x, b = blockIdx.x;
  const float* p = P + b*512;
  for (int r=0; r<4; ++r){
    for (int i=t; i<1024; i+=256) ss[i] = simr[((size_t)b*NN + i)*4 + r];
    __syncthreads();
    float mx = -1e30f;
    for (int i=t; i<1024; i+=256) mx = fmaxf(mx, ss[i]);
    red[t] = mx; __syncthreads();
    for (int s=128; s; s>>=1){ if (t<s) red[t] = fmaxf(red[t], red[t+s]); __syncthreads(); }
    mx = red[0]; __syncthreads();
    float sm = 0.f;
    for (int i=t; i<1024; i+=256){ float e = expf(ss[i]-mx); ss[i] = e; sm += e; }
    red[t] = sm; __syncthreads();
    for (int s=128; s; s>>=1){ if (t<s) red[t] += red[t+s]; __syncthreads(); }
    float inv = 1.f/red[0];
    float m0 = p[208+r], m1 = p[212+r], m2 = p[216+r];
    for (int i=t; i<1024; i+=256){
      size_t idx = ((size_t)b*NN + i)*4 + r;
      readw_out[idx] = bw[idx]*m0 + ss[i]*inv*m1 + fw[idx]*m2;
    }
    __syncthreads();
  }
}

// read_vec partial accumulation (8 n-chunks per batch)
__global__ void k_readvec(const float* __restrict__ mu, const float* __restrict__ readw,
                          float* __restrict__ rv_out){
  int t = threadIdx.x;
  int b = blockIdx.x >> 3, ch = blockIdx.x & 7;
  int w = t & 63, r = t >> 6;
  float acc = 0.f;
  for (int n = ch*128; n < ch*128+128; ++n){
    size_t row = (size_t)b*NN + n;
    acc += mu[row*64 + w] * readw[row*4 + r];
  }
  atomicAdd(&rv_out[b*256 + w*4 + r], acc);
}

// memory_output = flat(read_vec) @ W_out + b_out
__global__ void k_out(const float* __restrict__ rv, const float* __restrict__ Wout,
                      const float* __restrict__ bout, float* __restrict__ out0){
  __shared__ float srv[256];
  int t = threadIdx.x, b = blockIdx.x;
  srv[t] = rv[b*256 + t];
  __syncthreads();
  float acc = bout[t];
  for (int k=0; k<256; ++k) acc += srv[k]*Wout[k*256 + t];
  out0[b*256 + t] = acc;
}

extern "C" void kernel_launch(void* const* d_in, const int* in_sizes, int n_in,
                              void* d_out, int out_size, void* d_ws, size_t ws_size,
                              hipStream_t stream) {
  const float* itf   = (const float*)d_in[0];
  const float* mem   = (const float*)d_in[1];
  const float* rwts  = (const float*)d_in[2];
  const float* wwts  = (const float*)d_in[3];
  const float* usage = (const float*)d_in[4];
  const float* prec  = (const float*)d_in[5];
  const float* link  = (const float*)d_in[6];
  const float* Wout  = (const float*)d_in[7];
  const float* bout  = (const float*)d_in[8];

  float* out = (float*)d_out;
  float* o_memout   = out;                         // 8192
  float* o_mu       = out + 8192;                  // 2097152
  float* o_readw    = out + 8192 + 2097152;        // 131072
  float* o_writew   = o_readw + 131072;            // 32768
  float* o_readvec  = o_writew + 32768;            // 8192
  float* o_usage    = o_readvec + 8192;            // 32768
  float* o_precnew  = o_usage + 32768;             // 32768
  float* o_linknew  = o_precnew + 32768;           // 33554432

  float* ws = (float*)d_ws;
  float* P    = ws + WS_PARAMS;
  float* simw = ws + WS_SIMW;
  float* simr = ws + WS_SIMR;
  float* fw   = ws + WS_FW;
  float* bw   = ws + WS_BW;

  // zero fw+bw accumulators (contiguous) + read_vec output region
  k_zero<<<(262144+255)/256, 256, 0, stream>>>(fw, 262144);
  k_zero<<<(8192+255)/256, 256, 0, stream>>>(o_readvec, 8192);

  k_parse<<<BB, 256, 0, stream>>>(itf, P);
  k_usage_simw<<<BB*NN/4, 256, 0, stream>>>(mem, rwts, wwts, usage, P, simw, o_usage);
  k_alloc_write<<<BB, 1024, 0, stream>>>(simw, o_usage, prec, P, o_writew, o_precnew);
  k_memupd<<<BB*NN/4, 256, 0, stream>>>(mem, o_writew, P, o_mu, simr);
  k_link<<<BB*256, 256, 0, stream>>>(link, rwts, prec, o_writew, o_linknew, fw, bw);
  k_readw<<<BB, 256, 0, stream>>>(simr, fw, bw, P, o_readw);
  k_readvec<<<BB*8, 256, 0, stream>>>(o_mu, o_readw, o_readvec);
  k_out<<<BB, 256, 0, stream>>>(o_readvec, Wout, bout, o_memout);
}